// Round 5
// baseline (111.333 us; speedup 1.0000x reference)
//
#include <hip/hip_runtime.h>
#include <hip/hip_bf16.h>

#define ALPHA 0.2f
static __device__ __forceinline__ float lrel(float x) { return fmaxf(x, ALPHA * x); }

typedef __attribute__((ext_vector_type(8))) short bf16x8;
typedef __attribute__((ext_vector_type(4))) float f32x4;
typedef __attribute__((ext_vector_type(2))) float f32x2;

union FragU { bf16x8 v; unsigned int u[4]; uint4 q; };

static __device__ __forceinline__ unsigned int pk2(float a, float b) {
    unsigned int r;
    asm("v_cvt_pk_bf16_f32 %0, %1, %2" : "=v"(r) : "v"(a), "v"(b));
    return r;
}
static __device__ __forceinline__ f32x2 mk2(float a, float b) { f32x2 r; r.x = a; r.y = b; return r; }
static __device__ __forceinline__ f32x2 pkadd(f32x2 a, f32x2 b) {
    f32x2 r;
    asm("v_pk_add_f32 %0, %1, %2" : "=v"(r) : "v"(a), "v"(b));
    return r;
}
static __device__ __forceinline__ f32x2 pkmul(f32x2 a, f32x2 b) {
    f32x2 r;
    asm("v_pk_mul_f32 %0, %1, %2" : "=v"(r) : "v"(a), "v"(b));
    return r;
}
static __device__ __forceinline__ f32x2 lrel2(f32x2 x) {
    f32x2 c; c.x = ALPHA; c.y = ALPHA;
    f32x2 y = pkmul(x, c);
    f32x2 r; r.x = fmaxf(x.x, y.x); r.y = fmaxf(x.y, y.y);
    return r;
}
// lrel on a pair then convert to packed bf16 dword
static __device__ __forceinline__ unsigned int cvl(f32x2 s) {
    f32x2 l = lrel2(s);
    return pk2(l.x, l.y);
}

// ---------------- Kernel 1: U/V precompute + weight-fragment prep ----------------
__global__ __launch_bounds__(256) void k_uv(
    const float* __restrict__ x, const float* __restrict__ W0, const float* __restrict__ b0,
    const float* __restrict__ W1, const float* __restrict__ W2,
    float* __restrict__ U, float* __restrict__ V, unsigned int* __restrict__ WF)
{
    if (blockIdx.x == 1024) {
        const int t = threadIdx.x;
        const int l = t & 63, part = t >> 6;
        const int lo = l & 15, g = l >> 4;
#pragma unroll
        for (int q = 0; q < 2; ++q) {
            const int ff = part * 2 + q;           // 0..7 = (s*4+nf)
            const int s = ff >> 2, nf = ff & 3;
            const int pc = 32 * (nf >> 1) + 8 * (lo >> 2) + 4 * (nf & 1) + (lo & 3);
            const int c2 = 16 * nf + lo;
            unsigned int o1[4], o2[4];
#pragma unroll
            for (int uq = 0; uq < 4; ++uq) {
                const int k0 = 32 * s + 8 * g + 2 * uq;
                o1[uq] = pk2(W1[k0 * 64 + pc], W1[(k0 + 1) * 64 + pc]);
                o2[uq] = pk2(W2[k0 * 64 + c2], W2[(k0 + 1) * 64 + c2]);
            }
            *(uint4*)(WF + (ff * 64 + l) * 4)       = make_uint4(o1[0], o1[1], o1[2], o1[3]);
            *(uint4*)(WF + ((8 + ff) * 64 + l) * 4) = make_uint4(o2[0], o2[1], o2[2], o2[3]);
        }
        return;
    }
    int idx = blockIdx.x * 256 + threadIdx.x;
    int n = idx >> 6;
    int k = idx & 63;
    const float* xr = x + n * 32;
    float u = b0[k], v = 0.f;
#pragma unroll
    for (int f = 0; f < 32; ++f) {
        float xv = xr[f];
        u += xv * W0[f * 64 + k];
        v += xv * W0[(32 + f) * 64 + k];
    }
    U[idx] = u;
    V[idx] = v;
}

// ---------------- Kernel 2: edge MLP (layers 1,2) + sum over j ----------------
// LDS-staged V (double-buffered, XOR-chunk swizzle, shared by 4 i's per block).
// Transposed-GEMM + pi-permuted W1 (GEMM1 acc registers ARE GEMM2's B-fragment).
// Biases read from LDS broadcast as MFMA C-init. Packed-f32 VALU math.
__global__ __launch_bounds__(256, 4) void k_edge(
    const float* __restrict__ U, const float* __restrict__ V,
    const unsigned int* __restrict__ WF,
    const float* __restrict__ b1, const float* __restrict__ b2,
    float* __restrict__ AGG)
{
    __shared__ float lds[2176];  // [0,1024) buf0 | [1024,2048) buf1 | [2048,2112) b1L | [2112,2176) b2L
    const int tid = threadIdx.x;
    const int w = tid >> 6, l = tid & 63;
    const int lo = l & 15, g = l >> 4;
    const int bid = blockIdx.x;
    const int b = bid >> 7, ig = bid & 127;
    const int node = b * 512 + ig * 4 + w;

    // ---- weight fragments: 16 coalesced dwordx4 loads
    FragU w1f[2][4], w2f[2][4];
    const uint4* wp = (const uint4*)WF;
#pragma unroll
    for (int s = 0; s < 2; ++s)
#pragma unroll
        for (int nf = 0; nf < 4; ++nf) {
            w1f[s][nf].q = wp[(s * 4 + nf) * 64 + l];
            w2f[s][nf].q = wp[(8 + s * 4 + nf) * 64 + l];
        }

    // ---- stage biases into LDS (b1 pi-permuted, b2 plain)
    if (tid < 64) {
        const int nf = tid >> 4, r4 = tid & 15;
        const int gg = r4 >> 2, rr = r4 & 3;
        lds[2048 + tid] = b1[32 * (nf >> 1) + 8 * gg + 4 * (nf & 1) + rr];
        lds[2112 + tid] = b2[16 * nf + r4];
    }

    // ---- U fragment pairs for node i: k = 32s + 8g + e
    const float* up = U + node * 64 + 8 * g;
    const float4 ua = *(const float4*)(up);
    const float4 ub = *(const float4*)(up + 4);
    const float4 uc = *(const float4*)(up + 32);
    const float4 ud = *(const float4*)(up + 36);
    f32x2 u2[8];
    u2[0] = mk2(ua.x, ua.y); u2[1] = mk2(ua.z, ua.w);
    u2[2] = mk2(ub.x, ub.y); u2[3] = mk2(ub.z, ub.w);
    u2[4] = mk2(uc.x, uc.y); u2[5] = mk2(uc.z, uc.w);
    u2[6] = mk2(ud.x, ud.y); u2[7] = mk2(ud.z, ud.w);

    const float* Vb = V + b * 512 * 64;
    const int wr = tid >> 4, wm = tid & 15;
    const int woff = wr * 64 + ((wm ^ (wr & 7)) << 2);

    // ---- stage tile 0 into buf0
    {
        const float4 nv = *(const float4*)(Vb + wr * 64 + wm * 4);
        *(float4*)(lds + woff) = nv;
    }
    __syncthreads();

    // ---- swizzled read offsets (row lo, chunks 2g,2g+1,8+2g,9+2g)
    const int roff0 = lo * 64 + (((2 * g + 0) ^ (lo & 7)) << 2);
    const int roff1 = lo * 64 + (((2 * g + 1) ^ (lo & 7)) << 2);
    const int roff2 = lo * 64 + (((2 * g + 8) ^ (lo & 7)) << 2);
    const int roff3 = lo * 64 + (((2 * g + 9) ^ (lo & 7)) << 2);

    f32x2 agg2[4][2];
#pragma unroll
    for (int nf = 0; nf < 4; ++nf) { agg2[nf][0] = mk2(0.f, 0.f); agg2[nf][1] = mk2(0.f, 0.f); }

#pragma unroll 1
    for (int k = 0; k < 32; ++k) {
        const int cur = (k & 1) << 10, nxt = ((k + 1) & 1) << 10;
        // issue next tile's global load early (T14: issue-early / write-late)
        const int jn = (k < 31) ? (k + 1) * 16 : 0;
        const float4 nv = *(const float4*)(Vb + (jn + wr) * 64 + wm * 4);

        // current V fragment from LDS
        const float4 va = *(const float4*)(lds + cur + roff0);
        const float4 vb = *(const float4*)(lds + cur + roff1);
        const float4 vc = *(const float4*)(lds + cur + roff2);
        const float4 vd = *(const float4*)(lds + cur + roff3);

        // ---- h0 = lrelu(U_i + V_j) -> bf16 B-fragment (packed-f32 math)
        FragU A0, A1;
        A0.u[0] = cvl(pkadd(u2[0], mk2(va.x, va.y)));
        A0.u[1] = cvl(pkadd(u2[1], mk2(va.z, va.w)));
        A0.u[2] = cvl(pkadd(u2[2], mk2(vb.x, vb.y)));
        A0.u[3] = cvl(pkadd(u2[3], mk2(vb.z, vb.w)));
        A1.u[0] = cvl(pkadd(u2[4], mk2(vc.x, vc.y)));
        A1.u[1] = cvl(pkadd(u2[5], mk2(vc.z, vc.w)));
        A1.u[2] = cvl(pkadd(u2[6], mk2(vd.x, vd.y)));
        A1.u[3] = cvl(pkadd(u2[7], mk2(vd.z, vd.w)));

        // ---- GEMM1 (bias C-init from LDS broadcast)
        f32x4 acc1[4];
#pragma unroll
        for (int nf = 0; nf < 4; ++nf) {
            const f32x4 c1 = *(const f32x4*)(lds + 2048 + nf * 16 + 4 * g);
            acc1[nf] = __builtin_amdgcn_mfma_f32_16x16x32_bf16(w1f[0][nf].v, A0.v, c1, 0, 0, 0);
            acc1[nf] = __builtin_amdgcn_mfma_f32_16x16x32_bf16(w1f[1][nf].v, A1.v, acc1[nf], 0, 0, 0);
        }

        // ---- lrelu + pack (pi trick: regs are GEMM2's B-fragment)
        FragU p0, p1;
        p0.u[0] = cvl(mk2(acc1[0][0], acc1[0][1]));
        p0.u[1] = cvl(mk2(acc1[0][2], acc1[0][3]));
        p0.u[2] = cvl(mk2(acc1[1][0], acc1[1][1]));
        p0.u[3] = cvl(mk2(acc1[1][2], acc1[1][3]));
        p1.u[0] = cvl(mk2(acc1[2][0], acc1[2][1]));
        p1.u[1] = cvl(mk2(acc1[2][2], acc1[2][3]));
        p1.u[2] = cvl(mk2(acc1[3][0], acc1[3][1]));
        p1.u[3] = cvl(mk2(acc1[3][2], acc1[3][3]));

        // ---- GEMM2 (bias C-init from LDS broadcast)
        f32x4 acc2[4];
#pragma unroll
        for (int nf = 0; nf < 4; ++nf) {
            const f32x4 c2 = *(const f32x4*)(lds + 2112 + nf * 16 + 4 * g);
            acc2[nf] = __builtin_amdgcn_mfma_f32_16x16x32_bf16(w2f[0][nf].v, p0.v, c2, 0, 0, 0);
            acc2[nf] = __builtin_amdgcn_mfma_f32_16x16x32_bf16(w2f[1][nf].v, p1.v, acc2[nf], 0, 0, 0);
        }

        // ---- lrelu + accumulate (packed adds)
#pragma unroll
        for (int nf = 0; nf < 4; ++nf) {
            agg2[nf][0] = pkadd(agg2[nf][0], lrel2(mk2(acc2[nf][0], acc2[nf][1])));
            agg2[nf][1] = pkadd(agg2[nf][1], lrel2(mk2(acc2[nf][2], acc2[nf][3])));
        }

        // ---- write staged tile to the other buffer, then sync
        *(float4*)(lds + nxt + woff) = nv;
        __syncthreads();
    }

    // ---- reduce over the 16 edge-lanes (lo); lanes lo==0 hold full sums
    float aggv[4][4];
#pragma unroll
    for (int nf = 0; nf < 4; ++nf) {
        aggv[nf][0] = agg2[nf][0].x; aggv[nf][1] = agg2[nf][0].y;
        aggv[nf][2] = agg2[nf][1].x; aggv[nf][3] = agg2[nf][1].y;
    }
#pragma unroll
    for (int nf = 0; nf < 4; ++nf)
#pragma unroll
        for (int r = 0; r < 4; ++r) {
            float v = aggv[nf][r];
            v += __shfl_xor(v, 1);
            v += __shfl_xor(v, 2);
            v += __shfl_xor(v, 4);
            v += __shfl_xor(v, 8);
            aggv[nf][r] = v;
        }
    if (lo == 0) {
#pragma unroll
        for (int nf = 0; nf < 4; ++nf) {
            float4 o = {aggv[nf][0], aggv[nf][1], aggv[nf][2], aggv[nf][3]};
            *(float4*)(AGG + node * 64 + 16 * nf + 4 * g) = o;
        }
    }
}

// ---------------- Kernel 3: node MLP fn: [agg, x] -> 128 -> 128 -> 32 ----------------
__global__ __launch_bounds__(256) void k_fn(
    const float* __restrict__ AGG, const float* __restrict__ x,
    const float* __restrict__ W0, const float* __restrict__ b0,
    const float* __restrict__ W1, const float* __restrict__ b1,
    const float* __restrict__ W2, const float* __restrict__ b2,
    float* __restrict__ out)
{
    __shared__ float in96T[96][8];
    __shared__ float h1T[128][8];
    __shared__ float h2T[128][8];
    const int t = threadIdx.x;
    const int half = t >> 7, f = t & 127;
    const int node0 = blockIdx.x * 8;

    for (int idx = t; idx < 768; idx += 256) {
        int nn = idx & 7, k = idx >> 3;
        in96T[k][nn] = (k < 64) ? AGG[(node0 + nn) * 64 + k]
                                : x[(node0 + nn) * 32 + (k - 64)];
    }
    __syncthreads();

    {
        float a0 = b0[f], a1 = a0, a2 = a0, a3 = a0;
#pragma unroll 4
        for (int k = 0; k < 96; ++k) {
            const float4 iv = *(const float4*)(&in96T[k][4 * half]);
            const float wv = W0[k * 128 + f];
            a0 += iv.x * wv; a1 += iv.y * wv; a2 += iv.z * wv; a3 += iv.w * wv;
        }
        float4 o = {lrel(a0), lrel(a1), lrel(a2), lrel(a3)};
        *(float4*)(&h1T[f][4 * half]) = o;
    }
    __syncthreads();

    {
        float a0 = b1[f], a1 = a0, a2 = a0, a3 = a0;
#pragma unroll 4
        for (int k = 0; k < 128; ++k) {
            const float4 iv = *(const float4*)(&h1T[k][4 * half]);
            const float wv = W1[k * 128 + f];
            a0 += iv.x * wv; a1 += iv.y * wv; a2 += iv.z * wv; a3 += iv.w * wv;
        }
        float4 o = {lrel(a0), lrel(a1), lrel(a2), lrel(a3)};
        *(float4*)(&h2T[f][4 * half]) = o;
    }
    __syncthreads();

    {
        const int nn = t >> 5, fo = t & 31;
        float a = b2[fo];
#pragma unroll 4
        for (int k = 0; k < 128; ++k) a += h2T[k][nn] * W2[k * 32 + fo];
        out[(node0 + nn) * 32 + fo] = a;
    }
}

extern "C" void kernel_launch(void* const* d_in, const int* in_sizes, int n_in,
                              void* d_out, int out_size, void* d_ws, size_t ws_size,
                              hipStream_t stream)
{
    const float* x    = (const float*)d_in[0];
    const float* feW0 = (const float*)d_in[1];
    const float* feb0 = (const float*)d_in[2];
    const float* feW1 = (const float*)d_in[3];
    const float* feb1 = (const float*)d_in[4];
    const float* feW2 = (const float*)d_in[5];
    const float* feb2 = (const float*)d_in[6];
    const float* fnW0 = (const float*)d_in[7];
    const float* fnb0 = (const float*)d_in[8];
    const float* fnW1 = (const float*)d_in[9];
    const float* fnb1 = (const float*)d_in[10];
    const float* fnW2 = (const float*)d_in[11];
    const float* fnb2 = (const float*)d_in[12];
    float* out = (float*)d_out;

    // workspace: U (1MB) | V (1MB) | AGG (1MB) | WF (16KB)
    float* U   = (float*)d_ws;
    float* V   = U + 262144;
    float* AGG = V + 262144;
    unsigned int* WF = (unsigned int*)(AGG + 262144);

    hipLaunchKernelGGL(k_uv,   dim3(1025), dim3(256), 0, stream, x, feW0, feb0, feW1, feW2, U, V, WF);
    hipLaunchKernelGGL(k_edge, dim3(1024), dim3(256), 0, stream, U, V, WF, feb1, feb2, AGG);
    hipLaunchKernelGGL(k_fn,   dim3(512),  dim3(256), 0, stream, AGG, x, fnW0, fnb0, fnW1, fnb1, fnW2, fnb2, out);
}

// Round 6
// 85.754 us; speedup vs baseline: 1.2983x; 1.2983x over previous
//
#include <hip/hip_runtime.h>
#include <hip/hip_bf16.h>

#define ALPHA 0.2f
static __device__ __forceinline__ float lrel(float x) { return fmaxf(x, ALPHA * x); }

typedef __attribute__((ext_vector_type(8))) short bf16x8;
typedef __attribute__((ext_vector_type(4))) float f32x4;

union FragU { bf16x8 v; unsigned int u[4]; uint4 q; };

// pack two f32 -> one dword of 2 bf16 (RNE) via the HW instruction
static __device__ __forceinline__ unsigned int pk2(float a, float b) {
    unsigned int r;
    asm("v_cvt_pk_bf16_f32 %0, %1, %2" : "=v"(r) : "v"(a), "v"(b));
    return r;
}
// lrelu both, then pack to bf16 pair
static __device__ __forceinline__ unsigned int cvl2(float a, float b) {
    return pk2(lrel(a), lrel(b));
}
// f32 -> bf16 (RNE) scalar
static __device__ __forceinline__ unsigned short f2bf(float x) {
    union { float f; unsigned int u; } c;
    c.f = x;
    unsigned int r = c.u + 0x7FFFu + ((c.u >> 16) & 1u);
    return (unsigned short)(r >> 16);
}
// pi permutation on 64 features: slot(16nf+4a+r) -> 32(nf>>1)+8a+4(nf&1)+r
static __device__ __forceinline__ int pi64(int s) {
    return 32 * ((s >> 4) >> 1) + 8 * ((s >> 2) & 3) + 4 * ((s >> 4) & 1) + (s & 3);
}

// ---------------- Kernel 1: Upi = pi(x @ W0top + b0), x_bf, weight fragments ----------------
// blocks 0..1023: per (node, slot) Upi; threads with slot<32 also emit x_bf.
// block 1024: pack W0bot/W1/W2 into MFMA fragment layout (20 frags x 64 lanes x 4 dw).
__global__ __launch_bounds__(256) void k_uv(
    const float* __restrict__ x, const float* __restrict__ W0, const float* __restrict__ b0,
    const float* __restrict__ W1, const float* __restrict__ W2,
    float* __restrict__ Upi, unsigned short* __restrict__ xbf, unsigned int* __restrict__ WF)
{
    if (blockIdx.x == 1024) {
        const int t = threadIdx.x;
        const int l = t & 63, part = t >> 6;
        const int lo = l & 15, g = l >> 4;
        for (int ff = part; ff < 20; ff += 4) {
            unsigned int o[4];
            if (ff < 4) {
                // w0f[nf=ff]: A-frag of W0bot^T, K=32, pi-permuted output col
                const int nf = ff;
                const int pc = 32 * (nf >> 1) + 8 * (lo >> 2) + 4 * (nf & 1) + (lo & 3);
#pragma unroll
                for (int uq = 0; uq < 4; ++uq) {
                    const int k0 = 8 * g + 2 * uq;
                    o[uq] = pk2(W0[(32 + k0) * 64 + pc], W0[(33 + k0) * 64 + pc]);
                }
            } else if (ff < 12) {
                // w1f[s][nf]: pi-permuted output col
                const int s = (ff - 4) >> 2, nf = (ff - 4) & 3;
                const int pc = 32 * (nf >> 1) + 8 * (lo >> 2) + 4 * (nf & 1) + (lo & 3);
#pragma unroll
                for (int uq = 0; uq < 4; ++uq) {
                    const int k0 = 32 * s + 8 * g + 2 * uq;
                    o[uq] = pk2(W1[k0 * 64 + pc], W1[(k0 + 1) * 64 + pc]);
                }
            } else {
                // w2f[s][nf]: true output col
                const int s = (ff - 12) >> 2, nf = (ff - 12) & 3;
                const int c2 = 16 * nf + lo;
#pragma unroll
                for (int uq = 0; uq < 4; ++uq) {
                    const int k0 = 32 * s + 8 * g + 2 * uq;
                    o[uq] = pk2(W2[k0 * 64 + c2], W2[(k0 + 1) * 64 + c2]);
                }
            }
            *(uint4*)(WF + (ff * 64 + l) * 4) = make_uint4(o[0], o[1], o[2], o[3]);
        }
        return;
    }
    const int idx = blockIdx.x * 256 + threadIdx.x;  // 0 .. 262143
    const int n = idx >> 6;
    const int slot = idx & 63;
    const int f = pi64(slot);
    const float* xr = x + n * 32;
    float u = b0[f];
#pragma unroll
    for (int i = 0; i < 32; ++i) u += xr[i] * W0[i * 64 + f];
    Upi[idx] = u;
    if (slot < 32) xbf[n * 32 + slot] = f2bf(xr[slot]);
}

// ---------------- Kernel 2: edge MLP (all 3 layers on MFMA) + sum over j ----------------
// GEMM0: h0^T = lrelu(W0bot'^T @ xj^T + Upi-broadcast)  [K=32, xj raw bf16 from memory]
// GEMM1: h1^T = lrelu(W1'^T @ h0^T + b1')               [pi trick: acc regs ARE next B-frag]
// GEMM2: e^T  = lrelu(W2^T @ h1^T + b2), agg += e
// grid: 1024 blocks = 8(b) x 128(ig); 4 waves/block; 1 node i per wave, 512 j's.
__global__ __launch_bounds__(256, 2) void k_edge(
    const float* __restrict__ Upi, const unsigned short* __restrict__ xbf,
    const unsigned int* __restrict__ WF,
    const float* __restrict__ b1, const float* __restrict__ b2,
    float* __restrict__ AGG)
{
    const int tid = threadIdx.x;
    const int w = tid >> 6, l = tid & 63;
    const int lo = l & 15, g = l >> 4;
    const int bid = blockIdx.x;
    const int b = bid >> 7, ig = bid & 127;
    const int node = b * 512 + ig * 4 + w;

    // ---- weight fragments: 20 coalesced dwordx4 loads
    FragU w0f[4], w1f[2][4], w2f[2][4];
    const uint4* wp = (const uint4*)WF;
#pragma unroll
    for (int nf = 0; nf < 4; ++nf) w0f[nf].q = wp[nf * 64 + l];
#pragma unroll
    for (int s = 0; s < 2; ++s)
#pragma unroll
        for (int nf = 0; nf < 4; ++nf) {
            w1f[s][nf].q = wp[(4 + s * 4 + nf) * 64 + l];
            w2f[s][nf].q = wp[(12 + s * 4 + nf) * 64 + l];
        }

    // ---- per-i C-init for GEMM0: Upi[node][16nf+4g..+3] (broadcast over edges)
    f32x4 u0f[4];
#pragma unroll
    for (int nf = 0; nf < 4; ++nf) {
        const float4 t0 = *(const float4*)(Upi + node * 64 + nf * 16 + 4 * g);
        u0f[nf] = (f32x4){t0.x, t0.y, t0.z, t0.w};
    }
    // ---- bias C-inits: b1 pi-permuted, b2 true
    f32x4 b1f[4], b2f[4];
#pragma unroll
    for (int nf = 0; nf < 4; ++nf) {
        const float4 t1 = *(const float4*)(b1 + 32 * (nf >> 1) + 8 * g + 4 * (nf & 1));
        const float4 t2 = *(const float4*)(b2 + 16 * nf + 4 * g);
        b1f[nf] = (f32x4){t1.x, t1.y, t1.z, t1.w};
        b2f[nf] = (f32x4){t2.x, t2.y, t2.z, t2.w};
    }

    const unsigned short* xb = xbf + b * 512 * 32;
    // prefetch tile 0's xj fragment: lane = edge lo, k = 8g..8g+7
    FragU xj;
    xj.q = *(const uint4*)(xb + lo * 32 + 8 * g);

    f32x4 agg[4];
#pragma unroll
    for (int nf = 0; nf < 4; ++nf) { f32x4 z = {0.f, 0.f, 0.f, 0.f}; agg[nf] = z; }

#pragma unroll 1
    for (int k = 0; k < 32; ++k) {
        // prefetch next tile's xj (independent of everything below)
        const int jn = ((k + 1) & 31) * 16;
        FragU xjn;
        xjn.q = *(const uint4*)(xb + (jn + lo) * 32 + 8 * g);

        // ---- GEMM0: K=32, C = Upi broadcast
        f32x4 acc0[4];
#pragma unroll
        for (int nf = 0; nf < 4; ++nf)
            acc0[nf] = __builtin_amdgcn_mfma_f32_16x16x32_bf16(w0f[nf].v, xj.v, u0f[nf], 0, 0, 0);

        // ---- lrelu + pack: regs are GEMM1's B-fragment (pi trick)
        FragU q0, q1;
        q0.u[0] = cvl2(acc0[0][0], acc0[0][1]);
        q0.u[1] = cvl2(acc0[0][2], acc0[0][3]);
        q0.u[2] = cvl2(acc0[1][0], acc0[1][1]);
        q0.u[3] = cvl2(acc0[1][2], acc0[1][3]);
        q1.u[0] = cvl2(acc0[2][0], acc0[2][1]);
        q1.u[1] = cvl2(acc0[2][2], acc0[2][3]);
        q1.u[2] = cvl2(acc0[3][0], acc0[3][1]);
        q1.u[3] = cvl2(acc0[3][2], acc0[3][3]);

        // ---- GEMM1 (bias C-init)
        f32x4 acc1[4];
#pragma unroll
        for (int nf = 0; nf < 4; ++nf) {
            acc1[nf] = __builtin_amdgcn_mfma_f32_16x16x32_bf16(w1f[0][nf].v, q0.v, b1f[nf], 0, 0, 0);
            acc1[nf] = __builtin_amdgcn_mfma_f32_16x16x32_bf16(w1f[1][nf].v, q1.v, acc1[nf], 0, 0, 0);
        }

        // ---- lrelu + pack: regs are GEMM2's B-fragment (pi trick)
        FragU p0, p1;
        p0.u[0] = cvl2(acc1[0][0], acc1[0][1]);
        p0.u[1] = cvl2(acc1[0][2], acc1[0][3]);
        p0.u[2] = cvl2(acc1[1][0], acc1[1][1]);
        p0.u[3] = cvl2(acc1[1][2], acc1[1][3]);
        p1.u[0] = cvl2(acc1[2][0], acc1[2][1]);
        p1.u[1] = cvl2(acc1[2][2], acc1[2][3]);
        p1.u[2] = cvl2(acc1[3][0], acc1[3][1]);
        p1.u[3] = cvl2(acc1[3][2], acc1[3][3]);

        // ---- GEMM2 (bias C-init)
        f32x4 acc2[4];
#pragma unroll
        for (int nf = 0; nf < 4; ++nf) {
            acc2[nf] = __builtin_amdgcn_mfma_f32_16x16x32_bf16(w2f[0][nf].v, p0.v, b2f[nf], 0, 0, 0);
            acc2[nf] = __builtin_amdgcn_mfma_f32_16x16x32_bf16(w2f[1][nf].v, p1.v, acc2[nf], 0, 0, 0);
        }

        // ---- lrelu + accumulate
#pragma unroll
        for (int nf = 0; nf < 4; ++nf)
#pragma unroll
            for (int r = 0; r < 4; ++r) agg[nf][r] += lrel(acc2[nf][r]);

        xj = xjn;
    }

    // ---- reduce over the 16 edge-lanes (lo); lanes lo==0 hold full sums
#pragma unroll
    for (int nf = 0; nf < 4; ++nf)
#pragma unroll
        for (int r = 0; r < 4; ++r) {
            float v = agg[nf][r];
            v += __shfl_xor(v, 1);
            v += __shfl_xor(v, 2);
            v += __shfl_xor(v, 4);
            v += __shfl_xor(v, 8);
            agg[nf][r] = v;
        }
    if (lo == 0) {
#pragma unroll
        for (int nf = 0; nf < 4; ++nf) {
            float4 o = {agg[nf][0], agg[nf][1], agg[nf][2], agg[nf][3]};
            *(float4*)(AGG + node * 64 + 16 * nf + 4 * g) = o;
        }
    }
}

// ---------------- Kernel 3: node MLP fn: [agg, x] -> 128 -> 128 -> 32 ----------------
__global__ __launch_bounds__(256) void k_fn(
    const float* __restrict__ AGG, const float* __restrict__ x,
    const float* __restrict__ W0, const float* __restrict__ b0,
    const float* __restrict__ W1, const float* __restrict__ b1,
    const float* __restrict__ W2, const float* __restrict__ b2,
    float* __restrict__ out)
{
    __shared__ float in96T[96][8];
    __shared__ float h1T[128][8];
    __shared__ float h2T[128][8];
    const int t = threadIdx.x;
    const int half = t >> 7, f = t & 127;
    const int node0 = blockIdx.x * 8;

    for (int idx = t; idx < 768; idx += 256) {
        int nn = idx & 7, k = idx >> 3;
        in96T[k][nn] = (k < 64) ? AGG[(node0 + nn) * 64 + k]
                                : x[(node0 + nn) * 32 + (k - 64)];
    }
    __syncthreads();

    {
        float a0 = b0[f], a1 = a0, a2 = a0, a3 = a0;
#pragma unroll 4
        for (int k = 0; k < 96; ++k) {
            const float4 iv = *(const float4*)(&in96T[k][4 * half]);
            const float wv = W0[k * 128 + f];
            a0 += iv.x * wv; a1 += iv.y * wv; a2 += iv.z * wv; a3 += iv.w * wv;
        }
        float4 o = {lrel(a0), lrel(a1), lrel(a2), lrel(a3)};
        *(float4*)(&h1T[f][4 * half]) = o;
    }
    __syncthreads();

    {
        float a0 = b1[f], a1 = a0, a2 = a0, a3 = a0;
#pragma unroll 4
        for (int k = 0; k < 128; ++k) {
            const float4 iv = *(const float4*)(&h1T[k][4 * half]);
            const float wv = W1[k * 128 + f];
            a0 += iv.x * wv; a1 += iv.y * wv; a2 += iv.z * wv; a3 += iv.w * wv;
        }
        float4 o = {lrel(a0), lrel(a1), lrel(a2), lrel(a3)};
        *(float4*)(&h2T[f][4 * half]) = o;
    }
    __syncthreads();

    {
        const int nn = t >> 5, fo = t & 31;
        float a = b2[fo];
#pragma unroll 4
        for (int k = 0; k < 128; ++k) a += h2T[k][nn] * W2[k * 32 + fo];
        out[(node0 + nn) * 32 + fo] = a;
    }
}

extern "C" void kernel_launch(void* const* d_in, const int* in_sizes, int n_in,
                              void* d_out, int out_size, void* d_ws, size_t ws_size,
                              hipStream_t stream)
{
    const float* x    = (const float*)d_in[0];
    const float* feW0 = (const float*)d_in[1];
    const float* feb0 = (const float*)d_in[2];
    const float* feW1 = (const float*)d_in[3];
    const float* feb1 = (const float*)d_in[4];
    const float* feW2 = (const float*)d_in[5];
    const float* feb2 = (const float*)d_in[6];
    const float* fnW0 = (const float*)d_in[7];
    const float* fnb0 = (const float*)d_in[8];
    const float* fnW1 = (const float*)d_in[9];
    const float* fnb1 = (const float*)d_in[10];
    const float* fnW2 = (const float*)d_in[11];
    const float* fnb2 = (const float*)d_in[12];
    float* out = (float*)d_out;

    // workspace: Upi (1MB) | AGG (1MB) | xbf (256KB) | WF (20KB)
    float* Upi = (float*)d_ws;
    float* AGG = Upi + 262144;
    unsigned short* xbf = (unsigned short*)(AGG + 262144);
    unsigned int* WF = (unsigned int*)(xbf + 131072);

    hipLaunchKernelGGL(k_uv,   dim3(1025), dim3(256), 0, stream, x, feW0, feb0, feW1, feW2, Upi, xbf, WF);
    hipLaunchKernelGGL(k_edge, dim3(1024), dim3(256), 0, stream, Upi, xbf, WF, feb1, feb2, AGG);
    hipLaunchKernelGGL(k_fn,   dim3(512),  dim3(256), 0, stream, AGG, x, fnW0, fnb0, fnW1, fnb1, fnW2, fnb2, out);
}

// Round 7
// 83.141 us; speedup vs baseline: 1.3391x; 1.0314x over previous
//
#include <hip/hip_runtime.h>
#include <hip/hip_bf16.h>

#define ALPHA 0.2f
static __device__ __forceinline__ float lrel(float x) { return fmaxf(x, ALPHA * x); }

typedef __attribute__((ext_vector_type(8))) short bf16x8;
typedef __attribute__((ext_vector_type(4))) float f32x4;

union FragU { bf16x8 v; unsigned int u[4]; uint4 q; };

// pack two f32 -> one dword of 2 bf16 (RNE) via the HW instruction
static __device__ __forceinline__ unsigned int pk2(float a, float b) {
    unsigned int r;
    asm("v_cvt_pk_bf16_f32 %0, %1, %2" : "=v"(r) : "v"(a), "v"(b));
    return r;
}
// lrelu both, then pack to bf16 pair
static __device__ __forceinline__ unsigned int cvl2(float a, float b) {
    return pk2(lrel(a), lrel(b));
}
// f32 -> bf16 (RNE) scalar
static __device__ __forceinline__ unsigned short f2bf(float x) {
    union { float f; unsigned int u; } c;
    c.f = x;
    unsigned int r = c.u + 0x7FFFu + ((c.u >> 16) & 1u);
    return (unsigned short)(r >> 16);
}
// pi permutation on 64 features: slot(16nf+4a+r) -> 32(nf>>1)+8a+4(nf&1)+r
static __device__ __forceinline__ int pi64(int s) {
    return 32 * ((s >> 4) >> 1) + 8 * ((s >> 2) & 3) + 4 * ((s >> 4) & 1) + (s & 3);
}

// ---------------- Kernel 1: Upi = pi(x @ W0top + b0), x_bf, weight fragments ----------------
__global__ __launch_bounds__(256) void k_uv(
    const float* __restrict__ x, const float* __restrict__ W0, const float* __restrict__ b0,
    const float* __restrict__ W1, const float* __restrict__ W2,
    float* __restrict__ Upi, unsigned short* __restrict__ xbf, unsigned int* __restrict__ WF)
{
    if (blockIdx.x == 1024) {
        const int t = threadIdx.x;
        const int l = t & 63, part = t >> 6;
        const int lo = l & 15, g = l >> 4;
        for (int ff = part; ff < 20; ff += 4) {
            unsigned int o[4];
            if (ff < 4) {
                const int nf = ff;
                const int pc = 32 * (nf >> 1) + 8 * (lo >> 2) + 4 * (nf & 1) + (lo & 3);
#pragma unroll
                for (int uq = 0; uq < 4; ++uq) {
                    const int k0 = 8 * g + 2 * uq;
                    o[uq] = pk2(W0[(32 + k0) * 64 + pc], W0[(33 + k0) * 64 + pc]);
                }
            } else if (ff < 12) {
                const int s = (ff - 4) >> 2, nf = (ff - 4) & 3;
                const int pc = 32 * (nf >> 1) + 8 * (lo >> 2) + 4 * (nf & 1) + (lo & 3);
#pragma unroll
                for (int uq = 0; uq < 4; ++uq) {
                    const int k0 = 32 * s + 8 * g + 2 * uq;
                    o[uq] = pk2(W1[k0 * 64 + pc], W1[(k0 + 1) * 64 + pc]);
                }
            } else {
                const int s = (ff - 12) >> 2, nf = (ff - 12) & 3;
                const int c2 = 16 * nf + lo;
#pragma unroll
                for (int uq = 0; uq < 4; ++uq) {
                    const int k0 = 32 * s + 8 * g + 2 * uq;
                    o[uq] = pk2(W2[k0 * 64 + c2], W2[(k0 + 1) * 64 + c2]);
                }
            }
            *(uint4*)(WF + (ff * 64 + l) * 4) = make_uint4(o[0], o[1], o[2], o[3]);
        }
        return;
    }
    const int idx = blockIdx.x * 256 + threadIdx.x;
    const int n = idx >> 6;
    const int slot = idx & 63;
    const int f = pi64(slot);
    const float* xr = x + n * 32;
    float u = b0[f];
#pragma unroll
    for (int i = 0; i < 32; ++i) u += xr[i] * W0[i * 64 + f];
    Upi[idx] = u;
    if (slot < 32) xbf[n * 32 + slot] = f2bf(xr[slot]);
}

// ---------------- Kernel 2: edge MLP (all 3 layers on MFMA) + sum over j ----------------
// W1/W2 fragments streamed from LDS each iteration (register relief -> more waves/SIMD);
// W0 fragments + accumulators stay in registers. Opaque index defeats LICM so the
// ds_read_b128s stay in-loop. pi-permuted W0bot/W1 => acc regs ARE next GEMM's B-frag.
__global__ __launch_bounds__(256, 3) void k_edge(
    const float* __restrict__ Upi, const unsigned short* __restrict__ xbf,
    const unsigned int* __restrict__ WF,
    const float* __restrict__ b1, const float* __restrict__ b2,
    float* __restrict__ AGG)
{
    __shared__ uint4 wlds[1024];  // frags 4..19 of WF: [0..7]=w1f(s*4+nf), [8..15]=w2f
    const int tid = threadIdx.x;
    const int w = tid >> 6, l = tid & 63;
    const int lo = l & 15, g = l >> 4;
    const int bid = blockIdx.x;
    const int b = bid >> 7, ig = bid & 127;
    const int node = b * 512 + ig * 4 + w;

    // ---- stage W1/W2 fragments into LDS (once per block)
    for (int idx = tid; idx < 1024; idx += 256)
        wlds[idx] = ((const uint4*)WF)[256 + idx];

    // ---- W0bot fragments stay in registers (16 regs)
    FragU w0f[4];
    const uint4* wp = (const uint4*)WF;
#pragma unroll
    for (int nf = 0; nf < 4; ++nf) w0f[nf].q = wp[nf * 64 + l];

    // ---- per-i C-init for GEMM0 (Upi broadcast) + bias C-inits
    f32x4 u0f[4], b1f[4], b2f[4];
#pragma unroll
    for (int nf = 0; nf < 4; ++nf) {
        const float4 t0 = *(const float4*)(Upi + node * 64 + nf * 16 + 4 * g);
        u0f[nf] = (f32x4){t0.x, t0.y, t0.z, t0.w};
        const float4 t1 = *(const float4*)(b1 + 32 * (nf >> 1) + 8 * g + 4 * (nf & 1));
        const float4 t2 = *(const float4*)(b2 + 16 * nf + 4 * g);
        b1f[nf] = (f32x4){t1.x, t1.y, t1.z, t1.w};
        b2f[nf] = (f32x4){t2.x, t2.y, t2.z, t2.w};
    }

    const unsigned short* xb = xbf + b * 512 * 32;
    FragU xj;
    xj.q = *(const uint4*)(xb + lo * 32 + 8 * g);

    f32x4 agg[4];
#pragma unroll
    for (int nf = 0; nf < 4; ++nf) { f32x4 z = {0.f, 0.f, 0.f, 0.f}; agg[nf] = z; }

    __syncthreads();

#pragma unroll 1
    for (int k = 0; k < 32; ++k) {
        // opaque zero: defeats LICM on the LDS weight reads, keeps them in-loop
        int widx = 0;
        asm volatile("" : "+v"(widx));

        // prefetch next tile's xj
        const int jn = ((k + 1) & 31) * 16;
        FragU xjn;
        xjn.q = *(const uint4*)(xb + (jn + lo) * 32 + 8 * g);

        // ---- GEMM0: K=32, C = Upi broadcast
        f32x4 acc0[4];
#pragma unroll
        for (int nf = 0; nf < 4; ++nf)
            acc0[nf] = __builtin_amdgcn_mfma_f32_16x16x32_bf16(w0f[nf].v, xj.v, u0f[nf], 0, 0, 0);

        // ---- lrelu + pack: regs are GEMM1's B-fragment (pi trick)
        FragU q0, q1;
        q0.u[0] = cvl2(acc0[0][0], acc0[0][1]);
        q0.u[1] = cvl2(acc0[0][2], acc0[0][3]);
        q0.u[2] = cvl2(acc0[1][0], acc0[1][1]);
        q0.u[3] = cvl2(acc0[1][2], acc0[1][3]);
        q1.u[0] = cvl2(acc0[2][0], acc0[2][1]);
        q1.u[1] = cvl2(acc0[2][2], acc0[2][3]);
        q1.u[2] = cvl2(acc0[3][0], acc0[3][1]);
        q1.u[3] = cvl2(acc0[3][2], acc0[3][3]);

        // ---- GEMM1: W1 fragments from LDS (bias C-init)
        f32x4 acc1[4];
#pragma unroll
        for (int nf = 0; nf < 4; ++nf) {
            FragU wa, wb;
            wa.q = wlds[widx + nf * 64 + l];
            wb.q = wlds[widx + (4 + nf) * 64 + l];
            acc1[nf] = __builtin_amdgcn_mfma_f32_16x16x32_bf16(wa.v, q0.v, b1f[nf], 0, 0, 0);
            acc1[nf] = __builtin_amdgcn_mfma_f32_16x16x32_bf16(wb.v, q1.v, acc1[nf], 0, 0, 0);
        }

        // ---- lrelu + pack: regs are GEMM2's B-fragment (pi trick)
        FragU p0, p1;
        p0.u[0] = cvl2(acc1[0][0], acc1[0][1]);
        p0.u[1] = cvl2(acc1[0][2], acc1[0][3]);
        p0.u[2] = cvl2(acc1[1][0], acc1[1][1]);
        p0.u[3] = cvl2(acc1[1][2], acc1[1][3]);
        p1.u[0] = cvl2(acc1[2][0], acc1[2][1]);
        p1.u[1] = cvl2(acc1[2][2], acc1[2][3]);
        p1.u[2] = cvl2(acc1[3][0], acc1[3][1]);
        p1.u[3] = cvl2(acc1[3][2], acc1[3][3]);

        // ---- GEMM2: W2 fragments from LDS (bias C-init)
        f32x4 acc2[4];
#pragma unroll
        for (int nf = 0; nf < 4; ++nf) {
            FragU wa, wb;
            wa.q = wlds[widx + (8 + nf) * 64 + l];
            wb.q = wlds[widx + (12 + nf) * 64 + l];
            acc2[nf] = __builtin_amdgcn_mfma_f32_16x16x32_bf16(wa.v, p0.v, b2f[nf], 0, 0, 0);
            acc2[nf] = __builtin_amdgcn_mfma_f32_16x16x32_bf16(wb.v, p1.v, acc2[nf], 0, 0, 0);
        }

        // ---- lrelu + accumulate
#pragma unroll
        for (int nf = 0; nf < 4; ++nf)
#pragma unroll
            for (int r = 0; r < 4; ++r) agg[nf][r] += lrel(acc2[nf][r]);

        xj = xjn;
    }

    // ---- reduce over the 16 edge-lanes (lo); lanes lo==0 hold full sums
#pragma unroll
    for (int nf = 0; nf < 4; ++nf)
#pragma unroll
        for (int r = 0; r < 4; ++r) {
            float v = agg[nf][r];
            v += __shfl_xor(v, 1);
            v += __shfl_xor(v, 2);
            v += __shfl_xor(v, 4);
            v += __shfl_xor(v, 8);
            agg[nf][r] = v;
        }
    if (lo == 0) {
#pragma unroll
        for (int nf = 0; nf < 4; ++nf) {
            float4 o = {agg[nf][0], agg[nf][1], agg[nf][2], agg[nf][3]};
            *(float4*)(AGG + node * 64 + 16 * nf + 4 * g) = o;
        }
    }
}

// ---------------- Kernel 3: node MLP fn: [agg, x] -> 128 -> 128 -> 32 ----------------
__global__ __launch_bounds__(256) void k_fn(
    const float* __restrict__ AGG, const float* __restrict__ x,
    const float* __restrict__ W0, const float* __restrict__ b0,
    const float* __restrict__ W1, const float* __restrict__ b1,
    const float* __restrict__ W2, const float* __restrict__ b2,
    float* __restrict__ out)
{
    __shared__ float in96T[96][8];
    __shared__ float h1T[128][8];
    __shared__ float h2T[128][8];
    const int t = threadIdx.x;
    const int half = t >> 7, f = t & 127;
    const int node0 = blockIdx.x * 8;

    for (int idx = t; idx < 768; idx += 256) {
        int nn = idx & 7, k = idx >> 3;
        in96T[k][nn] = (k < 64) ? AGG[(node0 + nn) * 64 + k]
                                : x[(node0 + nn) * 32 + (k - 64)];
    }
    __syncthreads();

    {
        float a0 = b0[f], a1 = a0, a2 = a0, a3 = a0;
#pragma unroll 4
        for (int k = 0; k < 96; ++k) {
            const float4 iv = *(const float4*)(&in96T[k][4 * half]);
            const float wv = W0[k * 128 + f];
            a0 += iv.x * wv; a1 += iv.y * wv; a2 += iv.z * wv; a3 += iv.w * wv;
        }
        float4 o = {lrel(a0), lrel(a1), lrel(a2), lrel(a3)};
        *(float4*)(&h1T[f][4 * half]) = o;
    }
    __syncthreads();

    {
        float a0 = b1[f], a1 = a0, a2 = a0, a3 = a0;
#pragma unroll 4
        for (int k = 0; k < 128; ++k) {
            const float4 iv = *(const float4*)(&h1T[k][4 * half]);
            const float wv = W1[k * 128 + f];
            a0 += iv.x * wv; a1 += iv.y * wv; a2 += iv.z * wv; a3 += iv.w * wv;
        }
        float4 o = {lrel(a0), lrel(a1), lrel(a2), lrel(a3)};
        *(float4*)(&h2T[f][4 * half]) = o;
    }
    __syncthreads();

    {
        const int nn = t >> 5, fo = t & 31;
        float a = b2[fo];
#pragma unroll 4
        for (int k = 0; k < 128; ++k) a += h2T[k][nn] * W2[k * 32 + fo];
        out[(node0 + nn) * 32 + fo] = a;
    }
}

extern "C" void kernel_launch(void* const* d_in, const int* in_sizes, int n_in,
                              void* d_out, int out_size, void* d_ws, size_t ws_size,
                              hipStream_t stream)
{
    const float* x    = (const float*)d_in[0];
    const float* feW0 = (const float*)d_in[1];
    const float* feb0 = (const float*)d_in[2];
    const float* feW1 = (const float*)d_in[3];
    const float* feb1 = (const float*)d_in[4];
    const float* feW2 = (const float*)d_in[5];
    const float* feb2 = (const float*)d_in[6];
    const float* fnW0 = (const float*)d_in[7];
    const float* fnb0 = (const float*)d_in[8];
    const float* fnW1 = (const float*)d_in[9];
    const float* fnb1 = (const float*)d_in[10];
    const float* fnW2 = (const float*)d_in[11];
    const float* fnb2 = (const float*)d_in[12];
    float* out = (float*)d_out;

    // workspace: Upi (1MB) | AGG (1MB) | xbf (256KB) | WF (20KB)
    float* Upi = (float*)d_ws;
    float* AGG = Upi + 262144;
    unsigned short* xbf = (unsigned short*)(AGG + 262144);
    unsigned int* WF = (unsigned int*)(xbf + 131072);

    hipLaunchKernelGGL(k_uv,   dim3(1025), dim3(256), 0, stream, x, feW0, feb0, feW1, feW2, Upi, xbf, WF);
    hipLaunchKernelGGL(k_edge, dim3(1024), dim3(256), 0, stream, Upi, xbf, WF, feb1, feb2, AGG);
    hipLaunchKernelGGL(k_fn,   dim3(512),  dim3(256), 0, stream, AGG, x, fnW0, fnb0, fnW1, fnb1, fnW2, fnb2, out);
}

// Round 8
// 74.540 us; speedup vs baseline: 1.4936x; 1.1154x over previous
//
#include <hip/hip_runtime.h>
#include <hip/hip_bf16.h>

#define ALPHA 0.2f
static __device__ __forceinline__ float lrel(float x) { return fmaxf(x, ALPHA * x); }

typedef __attribute__((ext_vector_type(8))) short bf16x8;
typedef __attribute__((ext_vector_type(4))) float f32x4;

union FragU { bf16x8 v; unsigned int u[4]; uint4 q; };

// pack two f32 -> one dword of 2 bf16 (RNE) via the HW instruction
static __device__ __forceinline__ unsigned int pk2(float a, float b) {
    unsigned int r;
    asm("v_cvt_pk_bf16_f32 %0, %1, %2" : "=v"(r) : "v"(a), "v"(b));
    return r;
}
// lrelu both, then pack to bf16 pair
static __device__ __forceinline__ unsigned int cvl2(float a, float b) {
    return pk2(lrel(a), lrel(b));
}
// a += |x|  (VOP3 abs input modifier: single v_add)
static __device__ __forceinline__ void addabs(float& a, float x) {
    asm("v_add_f32 %0, %0, |%1|" : "+v"(a) : "v"(x));
}
// f32 -> bf16 (RNE) scalar
static __device__ __forceinline__ unsigned short f2bf(float x) {
    union { float f; unsigned int u; } c;
    c.f = x;
    unsigned int r = c.u + 0x7FFFu + ((c.u >> 16) & 1u);
    return (unsigned short)(r >> 16);
}
// pi permutation on 64 features: slot(16nf+4a+r) -> 32(nf>>1)+8a+4(nf&1)+r
static __device__ __forceinline__ int pi64(int s) {
    return 32 * ((s >> 4) >> 1) + 8 * ((s >> 2) & 3) + 4 * ((s >> 4) & 1) + (s & 3);
}

// ---------------- Kernel 1: Upi = pi(x @ W0top + b0), x_bf, weight fragments ----------------
__global__ __launch_bounds__(256) void k_uv(
    const float* __restrict__ x, const float* __restrict__ W0, const float* __restrict__ b0,
    const float* __restrict__ W1, const float* __restrict__ W2,
    float* __restrict__ Upi, unsigned short* __restrict__ xbf, unsigned int* __restrict__ WF)
{
    if (blockIdx.x == 1024) {
        const int t = threadIdx.x;
        const int l = t & 63, part = t >> 6;
        const int lo = l & 15, g = l >> 4;
        for (int ff = part; ff < 20; ff += 4) {
            unsigned int o[4];
            if (ff < 4) {
                const int nf = ff;
                const int pc = 32 * (nf >> 1) + 8 * (lo >> 2) + 4 * (nf & 1) + (lo & 3);
#pragma unroll
                for (int uq = 0; uq < 4; ++uq) {
                    const int k0 = 8 * g + 2 * uq;
                    o[uq] = pk2(W0[(32 + k0) * 64 + pc], W0[(33 + k0) * 64 + pc]);
                }
            } else if (ff < 12) {
                const int s = (ff - 4) >> 2, nf = (ff - 4) & 3;
                const int pc = 32 * (nf >> 1) + 8 * (lo >> 2) + 4 * (nf & 1) + (lo & 3);
#pragma unroll
                for (int uq = 0; uq < 4; ++uq) {
                    const int k0 = 32 * s + 8 * g + 2 * uq;
                    o[uq] = pk2(W1[k0 * 64 + pc], W1[(k0 + 1) * 64 + pc]);
                }
            } else {
                const int s = (ff - 12) >> 2, nf = (ff - 12) & 3;
                const int c2 = 16 * nf + lo;
#pragma unroll
                for (int uq = 0; uq < 4; ++uq) {
                    const int k0 = 32 * s + 8 * g + 2 * uq;
                    o[uq] = pk2(W2[k0 * 64 + c2], W2[(k0 + 1) * 64 + c2]);
                }
            }
            *(uint4*)(WF + (ff * 64 + l) * 4) = make_uint4(o[0], o[1], o[2], o[3]);
        }
        return;
    }
    const int idx = blockIdx.x * 256 + threadIdx.x;
    const int n = idx >> 6;
    const int slot = idx & 63;
    const int f = pi64(slot);
    const float* xr = x + n * 32;
    float u = b0[f];
#pragma unroll
    for (int i = 0; i < 32; ++i) u += xr[i] * W0[i * 64 + f];
    Upi[idx] = u;
    if (slot < 32) xbf[n * 32 + slot] = f2bf(xr[slot]);
}

// ---------------- Kernel 2: edge MLP (all 3 layers on MFMA) + sum over j ----------------
// Software-pipelined tile chain (skewed): GEMM0 computed one tile ahead; agg of the
// PREVIOUS tile's acc2 sits between GEMM1-issue and p-pack so VALU phases overlap
// in-flight MFMAs within the same wave. W1/W2 fragments streamed from LDS.
__global__ __launch_bounds__(256, 2) void k_edge(
    const float* __restrict__ Upi, const unsigned short* __restrict__ xbf,
    const unsigned int* __restrict__ WF,
    const float* __restrict__ b1, const float* __restrict__ b2,
    float* __restrict__ AGG)
{
    __shared__ uint4 wlds[1024];  // frags 4..19 of WF: [0..7]=w1f, [8..15]=w2f
    const int tid = threadIdx.x;
    const int w = tid >> 6, l = tid & 63;
    const int lo = l & 15, g = l >> 4;
    const int bid = blockIdx.x;
    const int b = bid >> 7, ig = bid & 127;
    const int node = b * 512 + ig * 4 + w;

    // ---- stage W1/W2 fragments into LDS (once per block)
    for (int idx = tid; idx < 1024; idx += 256)
        wlds[idx] = ((const uint4*)WF)[256 + idx];

    // ---- W0bot fragments in registers
    FragU w0f[4];
    const uint4* wp = (const uint4*)WF;
#pragma unroll
    for (int nf = 0; nf < 4; ++nf) w0f[nf].q = wp[nf * 64 + l];

    // ---- per-i C-init for GEMM0 (Upi broadcast) + bias C-inits
    f32x4 u0f[4], b1f[4], b2f[4];
#pragma unroll
    for (int nf = 0; nf < 4; ++nf) {
        const float4 t0 = *(const float4*)(Upi + node * 64 + nf * 16 + 4 * g);
        u0f[nf] = (f32x4){t0.x, t0.y, t0.z, t0.w};
        const float4 t1 = *(const float4*)(b1 + 32 * (nf >> 1) + 8 * g + 4 * (nf & 1));
        const float4 t2 = *(const float4*)(b2 + 16 * nf + 4 * g);
        b1f[nf] = (f32x4){t1.x, t1.y, t1.z, t1.w};
        b2f[nf] = (f32x4){t2.x, t2.y, t2.z, t2.w};
    }

    const unsigned short* xb = xbf + b * 512 * 32;

    // ---- prologue: xj for tiles 0,1; GEMM0 for tile 0
    FragU xjB, xjN;
    xjB.q = *(const uint4*)(xb + lo * 32 + 8 * g);          // tile 0
    xjN.q = *(const uint4*)(xb + (16 + lo) * 32 + 8 * g);   // tile 1

    __syncthreads();

    f32x4 acc0c[4];
#pragma unroll
    for (int nf = 0; nf < 4; ++nf)
        acc0c[nf] = __builtin_amdgcn_mfma_f32_16x16x32_bf16(w0f[nf].v, xjB.v, u0f[nf], 0, 0, 0);
    xjB = xjN;

    f32x4 acc2p[4];
#pragma unroll
    for (int nf = 0; nf < 4; ++nf) { f32x4 z = {0.f, 0.f, 0.f, 0.f}; acc2p[nf] = z; }

    float aggL[4][4], aggA[4][4];
#pragma unroll
    for (int nf = 0; nf < 4; ++nf)
#pragma unroll
        for (int r = 0; r < 4; ++r) { aggL[nf][r] = 0.f; aggA[nf][r] = 0.f; }

#pragma unroll 2
    for (int k = 0; k < 32; ++k) {
        // opaque zero: defeats LICM on the LDS weight reads
        int widx = 0;
        asm volatile("" : "+v"(widx));

        // load xj for tile k+2 (wraps; harmless garbage compute on last iter)
        const int jn = ((k + 2) & 31) * 16;
        FragU xjn;
        xjn.q = *(const uint4*)(xb + (jn + lo) * 32 + 8 * g);

        // ---- GEMM0 for tile k+1 (skewed one tile ahead)
        f32x4 acc0n[4];
#pragma unroll
        for (int nf = 0; nf < 4; ++nf)
            acc0n[nf] = __builtin_amdgcn_mfma_f32_16x16x32_bf16(w0f[nf].v, xjB.v, u0f[nf], 0, 0, 0);

        // ---- pack q from tile k's acc0 (overlaps GEMM0 MFMAs)
        FragU q0, q1;
        q0.u[0] = cvl2(acc0c[0][0], acc0c[0][1]);
        q0.u[1] = cvl2(acc0c[0][2], acc0c[0][3]);
        q0.u[2] = cvl2(acc0c[1][0], acc0c[1][1]);
        q0.u[3] = cvl2(acc0c[1][2], acc0c[1][3]);
        q1.u[0] = cvl2(acc0c[2][0], acc0c[2][1]);
        q1.u[1] = cvl2(acc0c[2][2], acc0c[2][3]);
        q1.u[2] = cvl2(acc0c[3][0], acc0c[3][1]);
        q1.u[3] = cvl2(acc0c[3][2], acc0c[3][3]);

        // ---- GEMM1 (W1 from LDS, bias C-init)
        f32x4 acc1[4];
#pragma unroll
        for (int nf = 0; nf < 4; ++nf) {
            FragU wa, wb;
            wa.q = wlds[widx + nf * 64 + l];
            wb.q = wlds[widx + (4 + nf) * 64 + l];
            acc1[nf] = __builtin_amdgcn_mfma_f32_16x16x32_bf16(wa.v, q0.v, b1f[nf], 0, 0, 0);
            acc1[nf] = __builtin_amdgcn_mfma_f32_16x16x32_bf16(wb.v, q1.v, acc1[nf], 0, 0, 0);
        }

        // ---- agg of PREVIOUS tile's acc2 (overlaps GEMM1 MFMAs)
#pragma unroll
        for (int nf = 0; nf < 4; ++nf)
#pragma unroll
            for (int r = 0; r < 4; ++r) {
                aggL[nf][r] += acc2p[nf][r];
                addabs(aggA[nf][r], acc2p[nf][r]);
            }

        // ---- pack p from acc1 (pi trick: regs are GEMM2's B-fragment)
        FragU p0, p1;
        p0.u[0] = cvl2(acc1[0][0], acc1[0][1]);
        p0.u[1] = cvl2(acc1[0][2], acc1[0][3]);
        p0.u[2] = cvl2(acc1[1][0], acc1[1][1]);
        p0.u[3] = cvl2(acc1[1][2], acc1[1][3]);
        p1.u[0] = cvl2(acc1[2][0], acc1[2][1]);
        p1.u[1] = cvl2(acc1[2][2], acc1[2][3]);
        p1.u[2] = cvl2(acc1[3][0], acc1[3][1]);
        p1.u[3] = cvl2(acc1[3][2], acc1[3][3]);

        // ---- GEMM2 (W2 from LDS, bias C-init) -> becomes "previous" for next iter
#pragma unroll
        for (int nf = 0; nf < 4; ++nf) {
            FragU wa, wb;
            wa.q = wlds[widx + (8 + nf) * 64 + l];
            wb.q = wlds[widx + (12 + nf) * 64 + l];
            acc2p[nf] = __builtin_amdgcn_mfma_f32_16x16x32_bf16(wa.v, p0.v, b2f[nf], 0, 0, 0);
            acc2p[nf] = __builtin_amdgcn_mfma_f32_16x16x32_bf16(wb.v, p1.v, acc2p[nf], 0, 0, 0);
        }

        // ---- rotate skew buffers (unroll-2 lets the allocator ping-pong, no copies)
#pragma unroll
        for (int nf = 0; nf < 4; ++nf) acc0c[nf] = acc0n[nf];
        xjB = xjn;
    }

    // ---- epilogue: agg the last tile's acc2
#pragma unroll
    for (int nf = 0; nf < 4; ++nf)
#pragma unroll
        for (int r = 0; r < 4; ++r) {
            aggL[nf][r] += acc2p[nf][r];
            addabs(aggA[nf][r], acc2p[nf][r]);
        }

    // ---- combine lrel parts, reduce over the 16 edge-lanes, store
#pragma unroll
    for (int nf = 0; nf < 4; ++nf)
#pragma unroll
        for (int r = 0; r < 4; ++r) {
            float v = 0.6f * aggL[nf][r] + 0.4f * aggA[nf][r];
            v += __shfl_xor(v, 1);
            v += __shfl_xor(v, 2);
            v += __shfl_xor(v, 4);
            v += __shfl_xor(v, 8);
            aggL[nf][r] = v;
        }
    if (lo == 0) {
#pragma unroll
        for (int nf = 0; nf < 4; ++nf) {
            float4 o = {aggL[nf][0], aggL[nf][1], aggL[nf][2], aggL[nf][3]};
            *(float4*)(AGG + node * 64 + 16 * nf + 4 * g) = o;
        }
    }
}

// ---------------- Kernel 3: node MLP fn: [agg, x] -> 128 -> 128 -> 32 ----------------
__global__ __launch_bounds__(256) void k_fn(
    const float* __restrict__ AGG, const float* __restrict__ x,
    const float* __restrict__ W0, const float* __restrict__ b0,
    const float* __restrict__ W1, const float* __restrict__ b1,
    const float* __restrict__ W2, const float* __restrict__ b2,
    float* __restrict__ out)
{
    __shared__ float in96T[96][8];
    __shared__ float h1T[128][8];
    __shared__ float h2T[128][8];
    const int t = threadIdx.x;
    const int half = t >> 7, f = t & 127;
    const int node0 = blockIdx.x * 8;

    for (int idx = t; idx < 768; idx += 256) {
        int nn = idx & 7, k = idx >> 3;
        in96T[k][nn] = (k < 64) ? AGG[(node0 + nn) * 64 + k]
                                : x[(node0 + nn) * 32 + (k - 64)];
    }
    __syncthreads();

    {
        float a0 = b0[f], a1 = a0, a2 = a0, a3 = a0;
#pragma unroll 4
        for (int k = 0; k < 96; ++k) {
            const float4 iv = *(const float4*)(&in96T[k][4 * half]);
            const float wv = W0[k * 128 + f];
            a0 += iv.x * wv; a1 += iv.y * wv; a2 += iv.z * wv; a3 += iv.w * wv;
        }
        float4 o = {lrel(a0), lrel(a1), lrel(a2), lrel(a3)};
        *(float4*)(&h1T[f][4 * half]) = o;
    }
    __syncthreads();

    {
        float a0 = b1[f], a1 = a0, a2 = a0, a3 = a0;
#pragma unroll 4
        for (int k = 0; k < 128; ++k) {
            const float4 iv = *(const float4*)(&h1T[k][4 * half]);
            const float wv = W1[k * 128 + f];
            a0 += iv.x * wv; a1 += iv.y * wv; a2 += iv.z * wv; a3 += iv.w * wv;
        }
        float4 o = {lrel(a0), lrel(a1), lrel(a2), lrel(a3)};
        *(float4*)(&h2T[f][4 * half]) = o;
    }
    __syncthreads();

    {
        const int nn = t >> 5, fo = t & 31;
        float a = b2[fo];
#pragma unroll 4
        for (int k = 0; k < 128; ++k) a += h2T[k][nn] * W2[k * 32 + fo];
        out[(node0 + nn) * 32 + fo] = a;
    }
}

extern "C" void kernel_launch(void* const* d_in, const int* in_sizes, int n_in,
                              void* d_out, int out_size, void* d_ws, size_t ws_size,
                              hipStream_t stream)
{
    const float* x    = (const float*)d_in[0];
    const float* feW0 = (const float*)d_in[1];
    const float* feb0 = (const float*)d_in[2];
    const float* feW1 = (const float*)d_in[3];
    const float* feb1 = (const float*)d_in[4];
    const float* feW2 = (const float*)d_in[5];
    const float* feb2 = (const float*)d_in[6];
    const float* fnW0 = (const float*)d_in[7];
    const float* fnb0 = (const float*)d_in[8];
    const float* fnW1 = (const float*)d_in[9];
    const float* fnb1 = (const float*)d_in[10];
    const float* fnW2 = (const float*)d_in[11];
    const float* fnb2 = (const float*)d_in[12];
    float* out = (float*)d_out;

    // workspace: Upi (1MB) | AGG (1MB) | xbf (256KB) | WF (20KB)
    float* Upi = (float*)d_ws;
    float* AGG = Upi + 262144;
    unsigned short* xbf = (unsigned short*)(AGG + 262144);
    unsigned int* WF = (unsigned int*)(xbf + 131072);

    hipLaunchKernelGGL(k_uv,   dim3(1025), dim3(256), 0, stream, x, feW0, feb0, feW1, feW2, Upi, xbf, WF);
    hipLaunchKernelGGL(k_edge, dim3(1024), dim3(256), 0, stream, Upi, xbf, WF, feb1, feb2, AGG);
    hipLaunchKernelGGL(k_fn,   dim3(512),  dim3(256), 0, stream, AGG, x, fnW0, fnb0, fnW1, fnb1, fnW2, fnb2, out);
}